// Round 6
// baseline (308.843 us; speedup 1.0000x reference)
//
#include <hip/hip_runtime.h>

#define K_DIM 4096
#define M_DIM 12288
#define KW (K_DIM / 4)      // packed int32 words per weight row = 1024
#define NT_K (K_DIM / 128)  // 32 K-tiles of 128 bytes
#define BT 128              // block tile (both dims)
#define GN2 32              // 4096/128 token tiles
#define GM2 96              // 12288/128 weight tiles

typedef __attribute__((ext_vector_type(4))) int i32x4;
typedef __attribute__((ext_vector_type(4))) unsigned int u32x4;

__device__ __forceinline__ int quant1(float v, float qs) {
  float r = rintf(v * qs);  // round half-to-even, matches jnp.round
  r = fminf(127.f, fmaxf(-128.f, r));
  return (int)r;
}

// unpack one packed byte into 4 code bytes (0..3) at permuted positions
__device__ __forceinline__ unsigned int unp(unsigned int uv) {
  return ((uv >> 6) | (uv << 4) | (uv << 14) | (uv << 24)) & 0x03030303u;
}

// One block per token row: absmax -> int8 quantize (k-permuted pack) + rowsum.
__global__ __launch_bounds__(256) void quant_kernel(const float* __restrict__ x,
                                                    unsigned int* __restrict__ xq,
                                                    float2* __restrict__ scales) {
  const int n = blockIdx.x;
  const int t = threadIdx.x;
  const float* __restrict__ row = x + (size_t)n * K_DIM;
  const float4* __restrict__ row4 = (const float4*)row;

  float am = 0.f;
#pragma unroll
  for (int p = 0; p < 4; ++p) {
    float4 v = row4[t + 256 * p];
    am = fmaxf(am, fmaxf(fmaxf(fabsf(v.x), fabsf(v.y)), fmaxf(fabsf(v.z), fabsf(v.w))));
  }
#pragma unroll
  for (int off = 32; off; off >>= 1) am = fmaxf(am, __shfl_xor(am, off, 64));
  __shared__ float redf[4];
  __shared__ int redi[4];
  const int wave = t >> 6, lane = t & 63;
  if (lane == 0) redf[wave] = am;
  __syncthreads();
  am = fmaxf(fmaxf(redf[0], redf[1]), fmaxf(redf[2], redf[3]));
  const float clipped = fmaxf(am, 1e-5f);
  const float qs = 127.0f / clipped;

  int rsum = 0;
#pragma unroll
  for (int p = 0; p < 4; ++p) {
    const int w = t + 256 * p;     // output word index 0..1023
    const int b = w >> 5, j = w & 31;
    const int base = b * 128 + j;  // source k for s=0
    const int q0 = quant1(row[base], qs);
    const int q1 = quant1(row[base + 32], qs);
    const int q2 = quant1(row[base + 64], qs);
    const int q3 = quant1(row[base + 96], qs);
    rsum += q0 + q1 + q2 + q3;
    xq[(size_t)n * KW + w] = (unsigned int)(q0 & 255) | ((unsigned int)(q1 & 255) << 8) |
                             ((unsigned int)(q2 & 255) << 16) | ((unsigned int)(q3 & 255) << 24);
  }
#pragma unroll
  for (int off = 32; off; off >>= 1) rsum += __shfl_xor(rsum, off, 64);
  if (lane == 0) redi[wave] = rsum;
  __syncthreads();
  if (t == 0)
    scales[n] = make_float2(clipped * (1.0f / 127.0f),
                            (float)(redi[0] + redi[1] + redi[2] + redi[3]));
}

// Pre-unpack all weights: packed int32 words -> int8 codes (0..3), k-permuted,
// linear row-major layout (same footprint as packed input).
__global__ __launch_bounds__(256) void unpack_kernel(const i32x4* __restrict__ in,
                                                     u32x4* __restrict__ outp, int n4) {
  int idx = blockIdx.x * 256 + threadIdx.x;
  const int stride = gridDim.x * 256;
  for (; idx < n4; idx += stride) {
    i32x4 v = in[idx];
    u32x4 u = {unp((unsigned int)v[0]), unp((unsigned int)v[1]),
               unp((unsigned int)v[2]), unp((unsigned int)v[3])};
    outp[idx] = u;
  }
}

// 128x128 tile, BK=128 B, 4 waves (2x2 grid, 64x64 each). Small block + low
// unified-reg footprint (~105 VGPR + 64 AGPR) + 64 KiB dbuf LDS => TWO
// independent blocks co-resident per CU (1 wave of each per SIMD): their
// unsynchronized phases overlap LDS-burst with MFMA-burst (m114 mechanism).
// XOR chunk swizzle (PMC-verified 0-conflict), counted vmcnt, XCD swizzle.
__global__ __launch_bounds__(256, 2) void bitgemm128(const unsigned char* __restrict__ xq,
                                                     const unsigned char* __restrict__ wu,
                                                     const float2* __restrict__ scales,
                                                     const float* __restrict__ wsp,
                                                     float* __restrict__ out) {
  __shared__ __align__(16) unsigned char lds[65536];  // A [2][128][128] | B [2][128][128]

  const int tid = threadIdx.x;
  const int l = tid & 63;
  const int w = tid >> 6;  // 0..3
  const int wm = w >> 1;   // row half 0..1
  const int wn = w & 1;    // col half 0..1

  // XCD swizzle: 3072 blocks (%8==0 -> bijective). Within an XCD, consecutive
  // blocks are bm-major => 64 co-resident blocks share one A-panel (L2-hot).
  const int cpx = gridDim.x >> 3;
  const int swz = (blockIdx.x & 7) * cpx + (blockIdx.x >> 3);
  const int bn = swz / GM2;  // token tile
  const int bm = swz % GM2;  // weight tile

  // staging: thread -> (row in 32-group, 16B chunk), source pre-swizzled.
  // row = q*32 + srow; (row&7)==(srow&7) so one schunk works for all q.
  const int srow = tid >> 3;
  const int schunk = (tid & 7) ^ (srow & 7);
  const size_t soff = (size_t)srow * K_DIM + (schunk << 4);
  const unsigned char* aSrc = xq + (size_t)(bn * BT) * K_DIM + soff;
  const unsigned char* bSrc = wu + (size_t)(bm * BT) * K_DIM + soff;
  const int ldsDst = tid * 16;  // = (srow*128 + (tid&7)*16); +q*4096 per 32-row group

  // fragment read byte-offsets; ks=1 toggles bit 6 ((ks*4+c)^r7 == ((c^r7))^(ks*4))
  int aoff[4], boff[4];
#pragma unroll
  for (int i = 0; i < 4; ++i) {
    const int ra = wm * 64 + i * 16 + (l & 15);
    aoff[i] = ra * 128 + (((l >> 4) ^ (ra & 7)) << 4);
    const int rb = wn * 64 + i * 16 + (l & 15);
    boff[i] = rb * 128 + (((l >> 4) ^ (rb & 7)) << 4);
  }

  i32x4 acc[4][4];
#pragma unroll
  for (int i = 0; i < 4; ++i)
#pragma unroll
    for (int j = 0; j < 4; ++j) acc[i][j] = (i32x4){0, 0, 0, 0};

  auto stage = [&](int buf, int kb) {
    unsigned char* ad = lds + buf * 16384 + ldsDst;
    unsigned char* bd = lds + 32768 + buf * 16384 + ldsDst;
    const unsigned char* as_ = aSrc + kb * 128;
    const unsigned char* bs_ = bSrc + kb * 128;
#pragma unroll
    for (int q = 0; q < 4; ++q) {
      __builtin_amdgcn_global_load_lds(
          (const __attribute__((address_space(1))) void*)(as_ + (size_t)q * 32 * K_DIM),
          (__attribute__((address_space(3))) void*)(ad + q * 4096), 16, 0, 0);
      __builtin_amdgcn_global_load_lds(
          (const __attribute__((address_space(1))) void*)(bs_ + (size_t)q * 32 * K_DIM),
          (__attribute__((address_space(3))) void*)(bd + q * 4096), 16, 0, 0);
    }
  };

  stage(0, 0);
  for (int kb = 0; kb < NT_K; ++kb) {
    const int cur = kb & 1;
    if (kb + 1 < NT_K) {
      stage(cur ^ 1, kb + 1);
      asm volatile("s_waitcnt vmcnt(8)" ::: "memory");  // prev tile landed; next in flight
    } else {
      asm volatile("s_waitcnt vmcnt(0)" ::: "memory");
    }
    __builtin_amdgcn_s_barrier();

    const unsigned char* Ab = lds + cur * 16384;
    const unsigned char* Bb = lds + 32768 + cur * 16384;
    // hoist all 16 frag reads (non-blocking), then 32 MFMAs; compiler inserts
    // counted lgkm waits so MFMA burst overlaps read latency within the wave,
    // while the co-resident sibling block overlaps at the CU level.
    i32x4 af[8], bf[8];
#pragma unroll
    for (int ks = 0; ks < 2; ++ks) {
#pragma unroll
      for (int i = 0; i < 4; ++i) {
        af[ks * 4 + i] = *(const i32x4*)(Ab + (aoff[i] ^ (ks << 6)));
        bf[ks * 4 + i] = *(const i32x4*)(Bb + (boff[i] ^ (ks << 6)));
      }
    }
    __builtin_amdgcn_s_setprio(1);
#pragma unroll
    for (int ks = 0; ks < 2; ++ks)
#pragma unroll
      for (int i = 0; i < 4; ++i)
#pragma unroll
        for (int j = 0; j < 4; ++j)
          acc[i][j] = __builtin_amdgcn_mfma_i32_16x16x64_i8(af[ks * 4 + i], bf[ks * 4 + j],
                                                            acc[i][j], 0, 0, 0);
    __builtin_amdgcn_s_setprio(0);
    __builtin_amdgcn_s_barrier();  // all reads of buf[cur] done before overwrite
  }

  // epilogue: out = (dot_codes - rowsum) * weight_scale * act_scale
  const float wsc = wsp[0];
#pragma unroll
  for (int i = 0; i < 4; ++i) {
#pragma unroll
    for (int r = 0; r < 4; ++r) {
      const int n = bn * BT + wm * 64 + i * 16 + ((l >> 4) << 2) + r;
      const float2 sc = scales[n];
      const float f = wsc * sc.x;
      float* orow = out + (size_t)n * M_DIM + bm * BT + wn * 64 + (l & 15);
#pragma unroll
      for (int j = 0; j < 4; ++j) orow[j * 16] = ((float)acc[i][j][r] - sc.y) * f;
    }
  }
}

extern "C" void kernel_launch(void* const* d_in, const int* in_sizes, int n_in,
                              void* d_out, int out_size, void* d_ws, size_t ws_size,
                              hipStream_t stream) {
  const float* x = (const float*)d_in[0];
  const int* wp = (const int*)d_in[1];
  const float* wsp = (const float*)d_in[2];
  float* out = (float*)d_out;
  const int N = in_sizes[0] / K_DIM;  // 4096 tokens

  float2* scales = (float2*)d_ws;                           // N * 8 B
  unsigned int* xq = (unsigned int*)((char*)d_ws + 32768);  // N * KW words
  const size_t xq_bytes = (size_t)N * KW * 4;
  unsigned char* wu = (unsigned char*)d_ws + 32768 + xq_bytes;  // M*K codes (linear)

  quant_kernel<<<N, 256, 0, stream>>>(x, xq, scales);
  unpack_kernel<<<2048, 256, 0, stream>>>((const i32x4*)wp, (u32x4*)wu, M_DIM * KW / 4);
  const int grid = GN2 * GM2;  // 32 * 96 = 3072
  bitgemm128<<<grid, 256, 0, stream>>>((const unsigned char*)xq, wu, scales, wsp, out);
}

// Round 7
// 239.031 us; speedup vs baseline: 1.2921x; 1.2921x over previous
//
#include <hip/hip_runtime.h>

#define K_DIM 4096
#define M_DIM 12288
#define KW 1024             // packed int32 words per weight row
#define NT_K 32             // K-tiles of 128 bytes
#define BM 256
#define BN 256
#define GN 16               // 4096/256 token tiles
#define GM 48               // 12288/256 weight tiles

typedef __attribute__((ext_vector_type(4))) int i32x4;
typedef __attribute__((ext_vector_type(16))) int i32x16;
typedef __attribute__((ext_vector_type(4))) unsigned int u32x4;
typedef __attribute__((ext_vector_type(4))) float f32x4;

__device__ __forceinline__ int quant1(float v, float qs) {
  float r = rintf(v * qs);  // round half-to-even, matches jnp.round
  r = fminf(127.f, fmaxf(-128.f, r));
  return (int)r;
}

// unpack one packed byte into 4 code bytes (0..3) at permuted positions
__device__ __forceinline__ unsigned int unp(unsigned int uv) {
  return ((uv >> 6) | (uv << 4) | (uv << 14) | (uv << 24)) & 0x03030303u;
}

// Fused aux kernel.
// blocks [0,4096): per-token absmax -> int8 quantize, k-major chunk output:
//   xq2 chunk16[c * 4096 + n] = codes for k' = 16c..16c+15 of token n.
// blocks [4096,5632): weight unpack+transpose into k-major:
//   wu2 chunk16[c * 12288 + m]. LDS-tiled so reads AND writes are coalesced.
__global__ __launch_bounds__(256) void aux_kernel(const float* __restrict__ x,
                                                  const int* __restrict__ wp,
                                                  u32x4* __restrict__ xq2,
                                                  u32x4* __restrict__ wu2,
                                                  float2* __restrict__ scales) {
  __shared__ float redf[4];
  __shared__ int redi[4];
  __shared__ u32x4 ldsT[32][9];  // padded: 8-lane groups conflict-free both phases
  const int t = threadIdx.x;

  if (blockIdx.x < 4096) {
    // ---------------- quant path: one block per token ----------------
    const int n = blockIdx.x;
    const f32x4* __restrict__ row4 = (const f32x4*)(x + (size_t)n * K_DIM);

    float am = 0.f;
#pragma unroll
    for (int p = 0; p < 4; ++p) {
      f32x4 v = row4[t + 256 * p];
      am = fmaxf(am, fmaxf(fmaxf(fabsf(v[0]), fabsf(v[1])), fmaxf(fabsf(v[2]), fabsf(v[3]))));
    }
#pragma unroll
    for (int off = 32; off; off >>= 1) am = fmaxf(am, __shfl_xor(am, off, 64));
    const int wave = t >> 6, lane = t & 63;
    if (lane == 0) redf[wave] = am;
    __syncthreads();
    am = fmaxf(fmaxf(redf[0], redf[1]), fmaxf(redf[2], redf[3]));
    const float clipped = fmaxf(am, 1e-5f);
    const float qs = 127.0f / clipped;

    // thread t produces output chunk c = t (k' = 16t..16t+15):
    // word m packs k = (t>>3)*128 + 4*(t&7) + m + 32s, s=0..3
    f32x4 v[4];
#pragma unroll
    for (int s = 0; s < 4; ++s) v[s] = row4[(t >> 3) * 32 + (t & 7) + 8 * s];
    unsigned int wds[4];
    int rsum = 0;
#pragma unroll
    for (int m = 0; m < 4; ++m) {
      const int q0 = quant1(v[0][m], qs);
      const int q1 = quant1(v[1][m], qs);
      const int q2 = quant1(v[2][m], qs);
      const int q3 = quant1(v[3][m], qs);
      rsum += q0 + q1 + q2 + q3;
      wds[m] = (unsigned int)(q0 & 255) | ((unsigned int)(q1 & 255) << 8) |
               ((unsigned int)(q2 & 255) << 16) | ((unsigned int)(q3 & 255) << 24);
    }
    xq2[(size_t)t * 4096 + n] = (u32x4){wds[0], wds[1], wds[2], wds[3]};

#pragma unroll
    for (int off = 32; off; off >>= 1) rsum += __shfl_xor(rsum, off, 64);
    if (lane == 0) redi[wave] = rsum;
    __syncthreads();
    if (t == 0)
      scales[n] = make_float2(clipped * (1.0f / 127.0f),
                              (float)(redi[0] + redi[1] + redi[2] + redi[3]));
  } else {
    // ---------------- weight unpack + transpose path ----------------
    const int bid = blockIdx.x - 4096;  // 48 m-tiles x 32 kb
    const int mt = bid >> 5, kb = bid & 31;
    const int m0 = mt * 256;
    const i32x4* __restrict__ in4 = (const i32x4*)wp;
#pragma unroll 2
    for (int it = 0; it < 8; ++it) {
      const int m = m0 + it * 32 + (t >> 3);
      const i32x4 vv = in4[(size_t)m * 256 + kb * 8 + (t & 7)];  // coalesced 128-B runs
      ldsT[t >> 3][t & 7] = (u32x4){unp((unsigned int)vv[0]), unp((unsigned int)vv[1]),
                                    unp((unsigned int)vv[2]), unp((unsigned int)vv[3])};
      __syncthreads();
      // write chunk-col c = kb*8 + (t>>5), rows m0+it*32+(t&31): coalesced 512-B runs
      wu2[(size_t)(kb * 8 + (t >> 5)) * M_DIM + m0 + it * 32 + (t & 31)] = ldsT[t & 31][t >> 5];
      __syncthreads();
    }
  }
}

// 256x256 tile, BK=128 B, 8 waves (2 row-halves x 4 col-quarters), wave-tile
// 128x64 via mfma_i32_32x32x32_i8 (4404 vs 3944 TOPS). LDS is k-chunk-major
// [2 buf][8 kc][256 row][16 B] per matrix: frag reads and staging are both
// 8-lane-contiguous => conflict-free, gload_lds sources fully coalesced.
// R2's counted-vmcnt 2-phase schedule (best measured), XCD block swizzle.
__global__ __launch_bounds__(512, 2) void bitgemm32(const unsigned char* __restrict__ xq2,
                                                    const unsigned char* __restrict__ wu2,
                                                    const float2* __restrict__ scales,
                                                    const float* __restrict__ wsp,
                                                    float* __restrict__ out) {
  __shared__ __align__(16) unsigned char lds[131072];  // A [2][32K] | B [2][32K]

  const int tid = threadIdx.x;
  const int l = tid & 63;
  const int w = tid >> 6;  // 0..7
  const int wm = w >> 2;   // row half 0..1
  const int wn = w & 3;    // col quarter 0..3

  // XCD swizzle: 768 blocks (%8==0 -> bijective), bm-major within each XCD
  const int cpx = gridDim.x >> 3;
  const int swz = (blockIdx.x & 7) * cpx + (blockIdx.x >> 3);
  const int bn = swz & (GN - 1);
  const int bm = swz >> 4;

  // staging: thread t writes LDS chunk-slot (q*2 + (t>>8), row t&255); source
  // chunk c = kb*8 + q*2 + (t>>8) at the same row -> contiguous 4-KiB runs.
  const unsigned char* aBase =
      xq2 + ((size_t)(tid >> 8) * 4096 + (size_t)bn * 256 + (tid & 255)) * 16;
  const unsigned char* bBase =
      wu2 + ((size_t)(tid >> 8) * 12288 + (size_t)bm * 256 + (tid & 255)) * 16;
  const int ldsDst = tid * 16;

  // fragment read base offsets: lane l -> k-half h = l>>5, row/col = l&31
  const int aFB = (l >> 5) * 4096 + (wm * 128 + (l & 31)) * 16;
  const int bFB = (l >> 5) * 4096 + (wn * 64 + (l & 31)) * 16;

  i32x16 acc[4][2];
#pragma unroll
  for (int i = 0; i < 4; ++i)
#pragma unroll
    for (int j = 0; j < 2; ++j)
#pragma unroll
      for (int r = 0; r < 16; ++r) acc[i][j][r] = 0;

  auto stage = [&](int buf, int kb) {
    unsigned char* ad = lds + buf * 32768 + ldsDst;
    unsigned char* bd = lds + 65536 + buf * 32768 + ldsDst;
    const unsigned char* as_ = aBase + (size_t)kb * 524288;   // kb*8 chunks * 4096 rows * 16B
    const unsigned char* bs_ = bBase + (size_t)kb * 1572864;  // kb*8 chunks * 12288 rows * 16B
#pragma unroll
    for (int q = 0; q < 4; ++q) {
      __builtin_amdgcn_global_load_lds(
          (const __attribute__((address_space(1))) void*)(as_ + (size_t)q * 131072),
          (__attribute__((address_space(3))) void*)(ad + q * 8192), 16, 0, 0);
      __builtin_amdgcn_global_load_lds(
          (const __attribute__((address_space(1))) void*)(bs_ + (size_t)q * 393216),
          (__attribute__((address_space(3))) void*)(bd + q * 8192), 16, 0, 0);
    }
  };

  stage(0, 0);
  for (int kb = 0; kb < NT_K; ++kb) {
    const int cur = kb & 1;
    if (kb + 1 < NT_K) {
      stage(cur ^ 1, kb + 1);
      asm volatile("s_waitcnt vmcnt(8)" ::: "memory");  // cur's 8 landed; next's in flight
    } else {
      asm volatile("s_waitcnt vmcnt(0)" ::: "memory");
    }
    __builtin_amdgcn_s_barrier();

    const unsigned char* Ab = lds + cur * 32768;
    const unsigned char* Bb = lds + 65536 + cur * 32768;
#pragma unroll
    for (int ks = 0; ks < 4; ++ks) {
      i32x4 af[4], bf[2];
#pragma unroll
      for (int i = 0; i < 4; ++i) af[i] = *(const i32x4*)(Ab + aFB + ks * 8192 + i * 512);
#pragma unroll
      for (int j = 0; j < 2; ++j) bf[j] = *(const i32x4*)(Bb + bFB + ks * 8192 + j * 512);
      __builtin_amdgcn_s_setprio(1);
#pragma unroll
      for (int i = 0; i < 4; ++i)
#pragma unroll
        for (int j = 0; j < 2; ++j)
          acc[i][j] = __builtin_amdgcn_mfma_i32_32x32x32_i8(af[i], bf[j], acc[i][j], 0, 0, 0);
      __builtin_amdgcn_s_setprio(0);
    }
    __builtin_amdgcn_s_barrier();
  }

  // epilogue: out = (dot_codes - rowsum) * weight_scale * act_scale
  // 32x32 C/D: col = l&31, row = (r&3) + 8*(r>>2) + 4*(l>>5)
  const float wsc = wsp[0];
#pragma unroll
  for (int i = 0; i < 4; ++i) {
#pragma unroll
    for (int r = 0; r < 16; ++r) {
      const int n = bn * BM + wm * 128 + i * 32 + (r & 3) + 8 * (r >> 2) + 4 * (l >> 5);
      const float2 sc = scales[n];
      const float f = wsc * sc.x;
      float* orow = out + (size_t)n * M_DIM + bm * BN + wn * 64 + (l & 31);
#pragma unroll
      for (int j = 0; j < 2; ++j) orow[j * 32] = ((float)acc[i][j][r] - sc.y) * f;
    }
  }
}

extern "C" void kernel_launch(void* const* d_in, const int* in_sizes, int n_in,
                              void* d_out, int out_size, void* d_ws, size_t ws_size,
                              hipStream_t stream) {
  const float* x = (const float*)d_in[0];
  const int* wp = (const int*)d_in[1];
  const float* wsp = (const float*)d_in[2];
  float* out = (float*)d_out;
  const int N = in_sizes[0] / K_DIM;  // 4096 tokens

  float2* scales = (float2*)d_ws;                               // N * 8 B
  u32x4* xq2 = (u32x4*)((char*)d_ws + 32768);                   // 16 MB, k-major
  u32x4* wu2 = (u32x4*)((char*)d_ws + 32768 + (size_t)N * K_DIM);  // 48 MB, k-major

  aux_kernel<<<4096 + 1536, 256, 0, stream>>>(x, wp, xq2, wu2, scales);
  const int grid = (N / BM) * GM;  // 768
  bitgemm32<<<grid, 512, 0, stream>>>((const unsigned char*)xq2, (const unsigned char*)wu2,
                                      scales, wsp, out);
}

// Round 8
// 236.281 us; speedup vs baseline: 1.3071x; 1.0116x over previous
//
#include <hip/hip_runtime.h>

#define K_DIM 4096
#define M_DIM 12288
#define KW 1024             // packed int32 words per weight row
#define NT_K 32             // K-tiles of 128 bytes
#define BM 256
#define BN 256
#define GN 16               // 4096/256 token tiles
#define GM 48               // 12288/256 weight tiles

typedef __attribute__((ext_vector_type(4))) int i32x4;
typedef __attribute__((ext_vector_type(16))) int i32x16;
typedef __attribute__((ext_vector_type(4))) unsigned int u32x4;
typedef __attribute__((ext_vector_type(4))) float f32x4;

__device__ __forceinline__ int quant1(float v, float qs) {
  float r = rintf(v * qs);  // round half-to-even, matches jnp.round
  r = fminf(127.f, fmaxf(-128.f, r));
  return (int)r;
}

// unpack one packed byte into 4 code bytes (0..3) at permuted positions
__device__ __forceinline__ unsigned int unp(unsigned int uv) {
  return ((uv >> 6) | (uv << 4) | (uv << 14) | (uv << 24)) & 0x03030303u;
}

// Fused aux kernel (identical to round-7 passing version).
__global__ __launch_bounds__(256) void aux_kernel(const float* __restrict__ x,
                                                  const int* __restrict__ wp,
                                                  u32x4* __restrict__ xq2,
                                                  u32x4* __restrict__ wu2,
                                                  float2* __restrict__ scales) {
  __shared__ float redf[4];
  __shared__ int redi[4];
  __shared__ u32x4 ldsT[32][9];  // padded: 8-lane groups conflict-free both phases
  const int t = threadIdx.x;

  if (blockIdx.x < 4096) {
    // ---------------- quant path: one block per token ----------------
    const int n = blockIdx.x;
    const f32x4* __restrict__ row4 = (const f32x4*)(x + (size_t)n * K_DIM);

    float am = 0.f;
#pragma unroll
    for (int p = 0; p < 4; ++p) {
      f32x4 v = row4[t + 256 * p];
      am = fmaxf(am, fmaxf(fmaxf(fabsf(v[0]), fabsf(v[1])), fmaxf(fabsf(v[2]), fabsf(v[3]))));
    }
#pragma unroll
    for (int off = 32; off; off >>= 1) am = fmaxf(am, __shfl_xor(am, off, 64));
    const int wave = t >> 6, lane = t & 63;
    if (lane == 0) redf[wave] = am;
    __syncthreads();
    am = fmaxf(fmaxf(redf[0], redf[1]), fmaxf(redf[2], redf[3]));
    const float clipped = fmaxf(am, 1e-5f);
    const float qs = 127.0f / clipped;

    // thread t produces output chunk c = t (k' = 16t..16t+15):
    // word m packs k = (t>>3)*128 + 4*(t&7) + m + 32s, s=0..3
    f32x4 v[4];
#pragma unroll
    for (int s = 0; s < 4; ++s) v[s] = row4[(t >> 3) * 32 + (t & 7) + 8 * s];
    unsigned int wds[4];
    int rsum = 0;
#pragma unroll
    for (int m = 0; m < 4; ++m) {
      const int q0 = quant1(v[0][m], qs);
      const int q1 = quant1(v[1][m], qs);
      const int q2 = quant1(v[2][m], qs);
      const int q3 = quant1(v[3][m], qs);
      rsum += q0 + q1 + q2 + q3;
      wds[m] = (unsigned int)(q0 & 255) | ((unsigned int)(q1 & 255) << 8) |
               ((unsigned int)(q2 & 255) << 16) | ((unsigned int)(q3 & 255) << 24);
    }
    xq2[(size_t)t * 4096 + n] = (u32x4){wds[0], wds[1], wds[2], wds[3]};

#pragma unroll
    for (int off = 32; off; off >>= 1) rsum += __shfl_xor(rsum, off, 64);
    if (lane == 0) redi[wave] = rsum;
    __syncthreads();
    if (t == 0)
      scales[n] = make_float2(clipped * (1.0f / 127.0f),
                              (float)(redi[0] + redi[1] + redi[2] + redi[3]));
  } else {
    // ---------------- weight unpack + transpose path ----------------
    const int bid = blockIdx.x - 4096;  // 48 m-tiles x 32 kb
    const int mt = bid >> 5, kb = bid & 31;
    const int m0 = mt * 256;
    const i32x4* __restrict__ in4 = (const i32x4*)wp;
#pragma unroll 2
    for (int it = 0; it < 8; ++it) {
      const int m = m0 + it * 32 + (t >> 3);
      const i32x4 vv = in4[(size_t)m * 256 + kb * 8 + (t & 7)];  // coalesced 128-B runs
      ldsT[t >> 3][t & 7] = (u32x4){unp((unsigned int)vv[0]), unp((unsigned int)vv[1]),
                                    unp((unsigned int)vv[2]), unp((unsigned int)vv[3])};
      __syncthreads();
      wu2[(size_t)(kb * 8 + (t >> 5)) * M_DIM + m0 + it * 32 + (t & 31)] = ldsT[t & 31][t >> 5];
      __syncthreads();
    }
  }
}

// explicit inline-asm ds_read with literal offset (prevents compiler batching)
#define DSR(dst, addr, off) \
  asm volatile("ds_read_b128 %0, %1 offset:" #off : "=v"(dst) : "v"(addr))
#define LGKM(n) asm volatile("s_waitcnt lgkmcnt(" #n ")")

// read the 6 fragments of one ks quadrant into slot s (literal offsets)
#define RD_KS0(s) { DSR(af[s][0], aA, 0);     DSR(af[s][1], aA, 512);   DSR(af[s][2], aA, 1024);  DSR(af[s][3], aA, 1536);  DSR(bf[s][0], bA, 0);     DSR(bf[s][1], bA, 512);   }
#define RD_KS1(s) { DSR(af[s][0], aA, 8192);  DSR(af[s][1], aA, 8704);  DSR(af[s][2], aA, 9216);  DSR(af[s][3], aA, 9728);  DSR(bf[s][0], bA, 8192);  DSR(bf[s][1], bA, 8704);  }
#define RD_KS2(s) { DSR(af[s][0], aA, 16384); DSR(af[s][1], aA, 16896); DSR(af[s][2], aA, 17408); DSR(af[s][3], aA, 17920); DSR(bf[s][0], bA, 16384); DSR(bf[s][1], bA, 16896); }
#define RD_KS3(s) { DSR(af[s][0], aA, 24576); DSR(af[s][1], aA, 25088); DSR(af[s][2], aA, 25600); DSR(af[s][3], aA, 26112); DSR(bf[s][0], bA, 24576); DSR(bf[s][1], bA, 25088); }

#define MFMA8(s)                                                                       \
  {                                                                                    \
    __builtin_amdgcn_s_setprio(1);                                                     \
    _Pragma("unroll") for (int i_ = 0; i_ < 4; ++i_)                                   \
        _Pragma("unroll") for (int j_ = 0; j_ < 2; ++j_) acc[i_][j_] =                 \
            __builtin_amdgcn_mfma_i32_32x32x32_i8(af[s][i_], bf[s][j_], acc[i_][j_],   \
                                                  0, 0, 0);                            \
    __builtin_amdgcn_s_setprio(0);                                                     \
  }

// 256x256 tile, BK=128 B, 8 waves, wave-tile 128x64, mfma_i32_32x32x32_i8.
// k-chunk-major LDS [2][8 kc][256 row][16 B] (conflict-free, PMC-verified).
// NEW: per-quadrant hand-counted lgkmcnt pipeline — each wave starts MFMA
// after ~1/4 of its reads instead of all 24, so waves' MFMA bursts overlap
// other waves' LDS reads (breaks completion-time lockstep).
__global__ __launch_bounds__(512, 2) void bitgemm32(const unsigned char* __restrict__ xq2,
                                                    const unsigned char* __restrict__ wu2,
                                                    const float2* __restrict__ scales,
                                                    const float* __restrict__ wsp,
                                                    float* __restrict__ out) {
  __shared__ __align__(16) unsigned char lds[131072];  // A [2][32K] | B [2][32K]

  const int tid = threadIdx.x;
  const int l = tid & 63;
  const int w = tid >> 6;  // 0..7
  const int wm = w >> 2;   // row half 0..1
  const int wn = w & 3;    // col quarter 0..3

  // XCD swizzle: 768 blocks (%8==0 -> bijective), bm-major within each XCD
  const int cpx = gridDim.x >> 3;
  const int swz = (blockIdx.x & 7) * cpx + (blockIdx.x >> 3);
  const int bn = swz & (GN - 1);
  const int bm = swz >> 4;

  // staging: thread t writes LDS chunk-slot (q*2 + (t>>8), row t&255); source
  // chunk c = kb*8 + q*2 + (t>>8) at the same row -> contiguous 4-KiB runs.
  const unsigned char* aBase =
      xq2 + ((size_t)(tid >> 8) * 4096 + (size_t)bn * 256 + (tid & 255)) * 16;
  const unsigned char* bBase =
      wu2 + ((size_t)(tid >> 8) * 12288 + (size_t)bm * 256 + (tid & 255)) * 16;
  const int ldsDst = tid * 16;

  // fragment read base offsets: lane l -> k-half h = l>>5, row/col = l&31
  const int aFB = (l >> 5) * 4096 + (wm * 128 + (l & 31)) * 16;
  const int bFB = (l >> 5) * 4096 + (wn * 64 + (l & 31)) * 16;
  const unsigned ldsBase = (unsigned)(size_t)lds;

  i32x16 acc[4][2];
#pragma unroll
  for (int i = 0; i < 4; ++i)
#pragma unroll
    for (int j = 0; j < 2; ++j)
#pragma unroll
      for (int r = 0; r < 16; ++r) acc[i][j][r] = 0;

  auto stage = [&](int buf, int kb) {
    unsigned char* ad = lds + buf * 32768 + ldsDst;
    unsigned char* bd = lds + 65536 + buf * 32768 + ldsDst;
    const unsigned char* as_ = aBase + (size_t)kb * 524288;   // kb*8 chunks * 4096 rows
    const unsigned char* bs_ = bBase + (size_t)kb * 1572864;  // kb*8 chunks * 12288 rows
#pragma unroll
    for (int q = 0; q < 4; ++q) {
      __builtin_amdgcn_global_load_lds(
          (const __attribute__((address_space(1))) void*)(as_ + (size_t)q * 131072),
          (__attribute__((address_space(3))) void*)(ad + q * 8192), 16, 0, 0);
      __builtin_amdgcn_global_load_lds(
          (const __attribute__((address_space(1))) void*)(bs_ + (size_t)q * 393216),
          (__attribute__((address_space(3))) void*)(bd + q * 8192), 16, 0, 0);
    }
  };

  i32x4 af[2][4], bf[2][4];

  stage(0, 0);
  for (int kb = 0; kb < NT_K; ++kb) {
    const int cur = kb & 1;
    if (kb + 1 < NT_K) {
      stage(cur ^ 1, kb + 1);
      asm volatile("s_waitcnt vmcnt(8)" ::: "memory");  // cur's 8 landed; next's in flight
    } else {
      asm volatile("s_waitcnt vmcnt(0)" ::: "memory");
    }
    __builtin_amdgcn_s_barrier();
    __builtin_amdgcn_sched_barrier(0);

    const unsigned aA = ldsBase + cur * 32768 + aFB;
    const unsigned bA = ldsBase + 65536 + cur * 32768 + bFB;

    // per-quadrant pipeline: 2 quadrants of reads in flight, wait for the
    // oldest 6 only, fence (rule #18), MFMA, issue next quadrant.
    RD_KS0(0);
    RD_KS1(1);
    LGKM(6);                              // ks0's 6 complete; ks1's in flight
    __builtin_amdgcn_sched_barrier(0);
    MFMA8(0);
    RD_KS2(0);
    LGKM(6);                              // ks1 complete; ks2 in flight
    __builtin_amdgcn_sched_barrier(0);
    MFMA8(1);
    RD_KS3(1);
    LGKM(6);                              // ks2 complete; ks3 in flight
    __builtin_amdgcn_sched_barrier(0);
    MFMA8(0);
    LGKM(0);                              // ks3 complete
    __builtin_amdgcn_sched_barrier(0);
    MFMA8(1);
    __builtin_amdgcn_s_barrier();         // all reads of buf[cur] done before overwrite
  }

  // epilogue: out = (dot_codes - rowsum) * weight_scale * act_scale
  // 32x32 C/D: col = l&31, row = (r&3) + 8*(r>>2) + 4*(l>>5)
  const float wsc = wsp[0];
#pragma unroll
  for (int i = 0; i < 4; ++i) {
#pragma unroll
    for (int r = 0; r < 16; ++r) {
      const int n = bn * BM + wm * 128 + i * 32 + (r & 3) + 8 * (r >> 2) + 4 * (l >> 5);
      const float2 sc = scales[n];
      const float f = wsc * sc.x;
      float* orow = out + (size_t)n * M_DIM + bm * BN + wn * 64 + (l & 31);
#pragma unroll
      for (int j = 0; j < 2; ++j) orow[j * 32] = ((float)acc[i][j][r] - sc.y) * f;
    }
  }
}

extern "C" void kernel_launch(void* const* d_in, const int* in_sizes, int n_in,
                              void* d_out, int out_size, void* d_ws, size_t ws_size,
                              hipStream_t stream) {
  const float* x = (const float*)d_in[0];
  const int* wp = (const int*)d_in[1];
  const float* wsp = (const float*)d_in[2];
  float* out = (float*)d_out;
  const int N = in_sizes[0] / K_DIM;  // 4096 tokens

  float2* scales = (float2*)d_ws;                               // N * 8 B
  u32x4* xq2 = (u32x4*)((char*)d_ws + 32768);                   // 16 MB, k-major
  u32x4* wu2 = (u32x4*)((char*)d_ws + 32768 + (size_t)N * K_DIM);  // 48 MB, k-major

  aux_kernel<<<4096 + 1536, 256, 0, stream>>>(x, wp, xq2, wu2, scales);
  const int grid = (N / BM) * GM;  // 768
  bitgemm32<<<grid, 512, 0, stream>>>((const unsigned char*)xq2, (const unsigned char*)wu2,
                                      scales, wsp, out);
}

// Round 9
// 234.827 us; speedup vs baseline: 1.3152x; 1.0062x over previous
//
#include <hip/hip_runtime.h>

#define K_DIM 4096
#define M_DIM 12288
#define KW 1024             // packed int32 words per weight row
#define NT_K 32             // K-tiles of 128 bytes
#define BM 256
#define BN 256
#define GN 16               // 4096/256 token tiles
#define GM 48               // 12288/256 weight tiles

typedef __attribute__((ext_vector_type(4))) int i32x4;
typedef __attribute__((ext_vector_type(16))) int i32x16;
typedef __attribute__((ext_vector_type(4))) unsigned int u32x4;
typedef __attribute__((ext_vector_type(4))) float f32x4;

__device__ __forceinline__ int quant1(float v, float qs) {
  float r = rintf(v * qs);  // round half-to-even, matches jnp.round
  r = fminf(127.f, fmaxf(-128.f, r));
  return (int)r;
}

// unpack one packed byte into 4 code bytes (0..3) at permuted positions
__device__ __forceinline__ unsigned int unp(unsigned int uv) {
  return ((uv >> 6) | (uv << 4) | (uv << 14) | (uv << 24)) & 0x03030303u;
}

// Fused aux kernel (identical to round-7/8 passing version).
__global__ __launch_bounds__(256) void aux_kernel(const float* __restrict__ x,
                                                  const int* __restrict__ wp,
                                                  u32x4* __restrict__ xq2,
                                                  u32x4* __restrict__ wu2,
                                                  float2* __restrict__ scales) {
  __shared__ float redf[4];
  __shared__ int redi[4];
  __shared__ u32x4 ldsT[32][9];  // padded: 8-lane groups conflict-free both phases
  const int t = threadIdx.x;

  if (blockIdx.x < 4096) {
    // ---------------- quant path: one block per token ----------------
    const int n = blockIdx.x;
    const f32x4* __restrict__ row4 = (const f32x4*)(x + (size_t)n * K_DIM);

    float am = 0.f;
#pragma unroll
    for (int p = 0; p < 4; ++p) {
      f32x4 v = row4[t + 256 * p];
      am = fmaxf(am, fmaxf(fmaxf(fabsf(v[0]), fabsf(v[1])), fmaxf(fabsf(v[2]), fabsf(v[3]))));
    }
#pragma unroll
    for (int off = 32; off; off >>= 1) am = fmaxf(am, __shfl_xor(am, off, 64));
    const int wave = t >> 6, lane = t & 63;
    if (lane == 0) redf[wave] = am;
    __syncthreads();
    am = fmaxf(fmaxf(redf[0], redf[1]), fmaxf(redf[2], redf[3]));
    const float clipped = fmaxf(am, 1e-5f);
    const float qs = 127.0f / clipped;

    // thread t produces output chunk c = t (k' = 16t..16t+15):
    // word m packs k = (t>>3)*128 + 4*(t&7) + m + 32s, s=0..3
    f32x4 v[4];
#pragma unroll
    for (int s = 0; s < 4; ++s) v[s] = row4[(t >> 3) * 32 + (t & 7) + 8 * s];
    unsigned int wds[4];
    int rsum = 0;
#pragma unroll
    for (int m = 0; m < 4; ++m) {
      const int q0 = quant1(v[0][m], qs);
      const int q1 = quant1(v[1][m], qs);
      const int q2 = quant1(v[2][m], qs);
      const int q3 = quant1(v[3][m], qs);
      rsum += q0 + q1 + q2 + q3;
      wds[m] = (unsigned int)(q0 & 255) | ((unsigned int)(q1 & 255) << 8) |
               ((unsigned int)(q2 & 255) << 16) | ((unsigned int)(q3 & 255) << 24);
    }
    xq2[(size_t)t * 4096 + n] = (u32x4){wds[0], wds[1], wds[2], wds[3]};

#pragma unroll
    for (int off = 32; off; off >>= 1) rsum += __shfl_xor(rsum, off, 64);
    if (lane == 0) redi[wave] = rsum;
    __syncthreads();
    if (t == 0)
      scales[n] = make_float2(clipped * (1.0f / 127.0f),
                              (float)(redi[0] + redi[1] + redi[2] + redi[3]));
  } else {
    // ---------------- weight unpack + transpose path ----------------
    const int bid = blockIdx.x - 4096;  // 48 m-tiles x 32 kb
    const int mt = bid >> 5, kb = bid & 31;
    const int m0 = mt * 256;
    const i32x4* __restrict__ in4 = (const i32x4*)wp;
#pragma unroll 2
    for (int it = 0; it < 8; ++it) {
      const int m = m0 + it * 32 + (t >> 3);
      const i32x4 vv = in4[(size_t)m * 256 + kb * 8 + (t & 7)];  // coalesced 128-B runs
      ldsT[t >> 3][t & 7] = (u32x4){unp((unsigned int)vv[0]), unp((unsigned int)vv[1]),
                                    unp((unsigned int)vv[2]), unp((unsigned int)vv[3])};
      __syncthreads();
      wu2[(size_t)(kb * 8 + (t >> 5)) * M_DIM + m0 + it * 32 + (t & 31)] = ldsT[t & 31][t >> 5];
      __syncthreads();
    }
  }
}

// explicit inline-asm ds_read with literal offset (prevents compiler batching)
#define DSR(dst, addr, off) \
  asm volatile("ds_read_b128 %0, %1 offset:" #off : "=v"(dst) : "v"(addr))
#define LGKM(n) asm volatile("s_waitcnt lgkmcnt(" #n ")")

// read the 8 fragments (4 A, 4 B) of one ks quadrant into slot s
#define RD_KS0(s) { DSR(af[s][0], aA, 0);     DSR(af[s][1], aA, 512);   DSR(af[s][2], aA, 1024);  DSR(af[s][3], aA, 1536);  DSR(bf[s][0], bA, 0);     DSR(bf[s][1], bA, 512);   DSR(bf[s][2], bA, 1024);  DSR(bf[s][3], bA, 1536);  }
#define RD_KS1(s) { DSR(af[s][0], aA, 8192);  DSR(af[s][1], aA, 8704);  DSR(af[s][2], aA, 9216);  DSR(af[s][3], aA, 9728);  DSR(bf[s][0], bA, 8192);  DSR(bf[s][1], bA, 8704);  DSR(bf[s][2], bA, 9216);  DSR(bf[s][3], bA, 9728);  }
#define RD_KS2(s) { DSR(af[s][0], aA, 16384); DSR(af[s][1], aA, 16896); DSR(af[s][2], aA, 17408); DSR(af[s][3], aA, 17920); DSR(bf[s][0], bA, 16384); DSR(bf[s][1], bA, 16896); DSR(bf[s][2], bA, 17408); DSR(bf[s][3], bA, 17920); }
#define RD_KS3(s) { DSR(af[s][0], aA, 24576); DSR(af[s][1], aA, 25088); DSR(af[s][2], aA, 25600); DSR(af[s][3], aA, 26112); DSR(bf[s][0], bA, 24576); DSR(bf[s][1], bA, 25088); DSR(bf[s][2], bA, 25600); DSR(bf[s][3], bA, 26112); }

#define MFMA16(s)                                                                      \
  {                                                                                    \
    __builtin_amdgcn_s_setprio(1);                                                     \
    _Pragma("unroll") for (int i_ = 0; i_ < 4; ++i_)                                   \
        _Pragma("unroll") for (int j_ = 0; j_ < 4; ++j_) acc[i_][j_] =                 \
            __builtin_amdgcn_mfma_i32_32x32x32_i8(af[s][i_], bf[s][j_], acc[i_][j_],   \
                                                  0, 0, 0);                            \
    __builtin_amdgcn_s_setprio(0);                                                     \
  }

// 256x256 block tile, BK=128 B, FOUR waves, wave-tile 128x128 (4x4 32x32
// frags, 256-AGPR accumulator, 1 wave/SIMD). Halves LDS read bytes per MFMA
// (0.5 KB vs 0.75): LDS pipe term 2140 cyc < MFMA term 2342 cyc per tile.
// Each SIMD's single wave free-runs the quadrant pipeline; the 4 waves tile
// the shared LDS pipe. k-chunk-major LDS (conflict-free, PMC-verified),
// counted vmcnt(16), XCD block swizzle.
__global__ __launch_bounds__(256, 1) void bitgemm44(const unsigned char* __restrict__ xq2,
                                                    const unsigned char* __restrict__ wu2,
                                                    const float2* __restrict__ scales,
                                                    const float* __restrict__ wsp,
                                                    float* __restrict__ out) {
  __shared__ __align__(16) unsigned char lds[131072];  // A [2][32K] | B [2][32K]

  const int tid = threadIdx.x;
  const int l = tid & 63;
  const int w = tid >> 6;  // 0..3
  const int wm = w >> 1;   // row half 0..1
  const int wn = w & 1;    // col half 0..1

  // XCD swizzle: 768 blocks (%8==0 -> bijective), bm-major within each XCD
  const int cpx = gridDim.x >> 3;
  const int swz = (blockIdx.x & 7) * cpx + (blockIdx.x >> 3);
  const int bn = swz & (GN - 1);
  const int bm = swz >> 4;

  // staging: thread t writes LDS slot (kc=q, row=t); source chunk kb*8+q,
  // same row -> each q is a contiguous, fully-coalesced 4-KiB run.
  const unsigned char* aBase = xq2 + ((size_t)bn * 256 + tid) * 16;
  const unsigned char* bBase = wu2 + ((size_t)bm * 256 + tid) * 16;
  const int ldsDst = tid * 16;

  // fragment read base offsets: lane l -> k-half h = l>>5, row/col = l&31
  const int aFB = (l >> 5) * 4096 + (wm * 128 + (l & 31)) * 16;
  const int bFB = (l >> 5) * 4096 + (wn * 128 + (l & 31)) * 16;
  const unsigned ldsBase = (unsigned)(size_t)lds;

  i32x16 acc[4][4];
#pragma unroll
  for (int i = 0; i < 4; ++i)
#pragma unroll
    for (int j = 0; j < 4; ++j)
#pragma unroll
      for (int r = 0; r < 16; ++r) acc[i][j][r] = 0;

  auto stage = [&](int buf, int kb) {
    unsigned char* ad = lds + buf * 32768 + ldsDst;
    unsigned char* bd = lds + 65536 + buf * 32768 + ldsDst;
    const unsigned char* as_ = aBase + (size_t)kb * 524288;   // kb*8 chunks * 4096 rows
    const unsigned char* bs_ = bBase + (size_t)kb * 1572864;  // kb*8 chunks * 12288 rows
#pragma unroll
    for (int q = 0; q < 8; ++q) {
      __builtin_amdgcn_global_load_lds(
          (const __attribute__((address_space(1))) void*)(as_ + (size_t)q * 65536),
          (__attribute__((address_space(3))) void*)(ad + q * 4096), 16, 0, 0);
      __builtin_amdgcn_global_load_lds(
          (const __attribute__((address_space(1))) void*)(bs_ + (size_t)q * 196608),
          (__attribute__((address_space(3))) void*)(bd + q * 4096), 16, 0, 0);
    }
  };

  i32x4 af[2][4], bf[2][4];

  stage(0, 0);
  for (int kb = 0; kb < NT_K; ++kb) {
    const int cur = kb & 1;
    if (kb + 1 < NT_K) {
      stage(cur ^ 1, kb + 1);
      asm volatile("s_waitcnt vmcnt(16)" ::: "memory");  // cur's 16 landed; next's in flight
    } else {
      asm volatile("s_waitcnt vmcnt(0)" ::: "memory");
    }
    __builtin_amdgcn_s_barrier();
    __builtin_amdgcn_sched_barrier(0);

    const unsigned aA = ldsBase + cur * 32768 + aFB;
    const unsigned bA = ldsBase + 65536 + cur * 32768 + bFB;

    // per-quadrant pipeline: 2 quadrants of reads in flight, wait for the
    // oldest 8 only, fence (rule #18), MFMA, issue next quadrant.
    RD_KS0(0);
    RD_KS1(1);
    LGKM(8);                              // ks0's 8 complete; ks1's in flight
    __builtin_amdgcn_sched_barrier(0);
    MFMA16(0);
    RD_KS2(0);
    LGKM(8);                              // ks1 complete; ks2 in flight
    __builtin_amdgcn_sched_barrier(0);
    MFMA16(1);
    RD_KS3(1);
    LGKM(8);                              // ks2 complete; ks3 in flight
    __builtin_amdgcn_sched_barrier(0);
    MFMA16(0);
    LGKM(0);                              // ks3 complete
    __builtin_amdgcn_sched_barrier(0);
    MFMA16(1);
    __builtin_amdgcn_s_barrier();         // all reads of buf[cur] done before overwrite
  }

  // epilogue: out = (dot_codes - rowsum) * weight_scale * act_scale
  // 32x32 C/D: col = l&31, row = (r&3) + 8*(r>>2) + 4*(l>>5)
  const float wsc = wsp[0];
#pragma unroll
  for (int i = 0; i < 4; ++i) {
#pragma unroll
    for (int r = 0; r < 16; ++r) {
      const int n = bn * BM + wm * 128 + i * 32 + (r & 3) + 8 * (r >> 2) + 4 * (l >> 5);
      const float2 sc = scales[n];
      const float f = wsc * sc.x;
      float* orow = out + (size_t)n * M_DIM + bm * BN + wn * 128 + (l & 31);
#pragma unroll
      for (int j = 0; j < 4; ++j) orow[j * 32] = ((float)acc[i][j][r] - sc.y) * f;
    }
  }
}

extern "C" void kernel_launch(void* const* d_in, const int* in_sizes, int n_in,
                              void* d_out, int out_size, void* d_ws, size_t ws_size,
                              hipStream_t stream) {
  const float* x = (const float*)d_in[0];
  const int* wp = (const int*)d_in[1];
  const float* wsp = (const float*)d_in[2];
  float* out = (float*)d_out;
  const int N = in_sizes[0] / K_DIM;  // 4096 tokens

  float2* scales = (float2*)d_ws;                                  // N * 8 B
  u32x4* xq2 = (u32x4*)((char*)d_ws + 32768);                      // 16 MB, k-major
  u32x4* wu2 = (u32x4*)((char*)d_ws + 32768 + (size_t)N * K_DIM);  // 48 MB, k-major

  aux_kernel<<<4096 + 1536, 256, 0, stream>>>(x, wp, xq2, wu2, scales);
  const int grid = (N / BM) * GM;  // 768
  bitgemm44<<<grid, 256, 0, stream>>>((const unsigned char*)xq2, (const unsigned char*)wu2,
                                      scales, wsp, out);
}

// Round 11
// 229.575 us; speedup vs baseline: 1.3453x; 1.0229x over previous
//
#include <hip/hip_runtime.h>

#define K_DIM 4096
#define M_DIM 12288
#define KW 1024             // packed int32 words per weight row
#define NT_K 32             // K-tiles of 128 bytes
#define BM 256
#define BN 256
#define GN 16               // 4096/256 token tiles
#define GM 48               // 12288/256 weight tiles

typedef __attribute__((ext_vector_type(4))) int i32x4;
typedef __attribute__((ext_vector_type(16))) int i32x16;
typedef __attribute__((ext_vector_type(4))) unsigned int u32x4;
typedef __attribute__((ext_vector_type(4))) float f32x4;

__device__ __forceinline__ int quant1(float v, float qs) {
  float r = rintf(v * qs);  // round half-to-even, matches jnp.round
  r = fminf(127.f, fmaxf(-128.f, r));
  return (int)r;
}

// unpack one packed byte into 4 code bytes (0..3) at permuted positions
__device__ __forceinline__ unsigned int unp(unsigned int uv) {
  return ((uv >> 6) | (uv << 4) | (uv << 14) | (uv << 24)) & 0x03030303u;
}

// Fused aux kernel (identical to round-7/8/9 passing version).
__global__ __launch_bounds__(256) void aux_kernel(const float* __restrict__ x,
                                                  const int* __restrict__ wp,
                                                  u32x4* __restrict__ xq2,
                                                  u32x4* __restrict__ wu2,
                                                  float2* __restrict__ scales) {
  __shared__ float redf[4];
  __shared__ int redi[4];
  __shared__ u32x4 ldsT[32][9];  // padded: 8-lane groups conflict-free both phases
  const int t = threadIdx.x;

  if (blockIdx.x < 4096) {
    // ---------------- quant path: one block per token ----------------
    const int n = blockIdx.x;
    const f32x4* __restrict__ row4 = (const f32x4*)(x + (size_t)n * K_DIM);

    float am = 0.f;
#pragma unroll
    for (int p = 0; p < 4; ++p) {
      f32x4 v = row4[t + 256 * p];
      am = fmaxf(am, fmaxf(fmaxf(fabsf(v[0]), fabsf(v[1])), fmaxf(fabsf(v[2]), fabsf(v[3]))));
    }
#pragma unroll
    for (int off = 32; off; off >>= 1) am = fmaxf(am, __shfl_xor(am, off, 64));
    const int wave = t >> 6, lane = t & 63;
    if (lane == 0) redf[wave] = am;
    __syncthreads();
    am = fmaxf(fmaxf(redf[0], redf[1]), fmaxf(redf[2], redf[3]));
    const float clipped = fmaxf(am, 1e-5f);
    const float qs = 127.0f / clipped;

    // thread t produces output chunk c = t (k' = 16t..16t+15):
    // word m packs k = (t>>3)*128 + 4*(t&7) + m + 32s, s=0..3
    f32x4 v[4];
#pragma unroll
    for (int s = 0; s < 4; ++s) v[s] = row4[(t >> 3) * 32 + (t & 7) + 8 * s];
    unsigned int wds[4];
    int rsum = 0;
#pragma unroll
    for (int m = 0; m < 4; ++m) {
      const int q0 = quant1(v[0][m], qs);
      const int q1 = quant1(v[1][m], qs);
      const int q2 = quant1(v[2][m], qs);
      const int q3 = quant1(v[3][m], qs);
      rsum += q0 + q1 + q2 + q3;
      wds[m] = (unsigned int)(q0 & 255) | ((unsigned int)(q1 & 255) << 8) |
               ((unsigned int)(q2 & 255) << 16) | ((unsigned int)(q3 & 255) << 24);
    }
    xq2[(size_t)t * 4096 + n] = (u32x4){wds[0], wds[1], wds[2], wds[3]};

#pragma unroll
    for (int off = 32; off; off >>= 1) rsum += __shfl_xor(rsum, off, 64);
    if (lane == 0) redi[wave] = rsum;
    __syncthreads();
    if (t == 0)
      scales[n] = make_float2(clipped * (1.0f / 127.0f),
                              (float)(redi[0] + redi[1] + redi[2] + redi[3]));
  } else {
    // ---------------- weight unpack + transpose path ----------------
    const int bid = blockIdx.x - 4096;  // 48 m-tiles x 32 kb
    const int mt = bid >> 5, kb = bid & 31;
    const int m0 = mt * 256;
    const i32x4* __restrict__ in4 = (const i32x4*)wp;
#pragma unroll 2
    for (int it = 0; it < 8; ++it) {
      const int m = m0 + it * 32 + (t >> 3);
      const i32x4 vv = in4[(size_t)m * 256 + kb * 8 + (t & 7)];  // coalesced 128-B runs
      ldsT[t >> 3][t & 7] = (u32x4){unp((unsigned int)vv[0]), unp((unsigned int)vv[1]),
                                    unp((unsigned int)vv[2]), unp((unsigned int)vv[3])};
      __syncthreads();
      wu2[(size_t)(kb * 8 + (t >> 5)) * M_DIM + m0 + it * 32 + (t & 31)] = ldsT[t & 31][t >> 5];
      __syncthreads();
    }
  }
}

// explicit inline-asm ds_read with literal offset (prevents compiler batching)
#define DSR(dst, addr, off) \
  asm volatile("ds_read_b128 %0, %1 offset:" #off : "=v"(dst) : "v"(addr))
#define LGKM(n) asm volatile("s_waitcnt lgkmcnt(" #n ")")

// read the 6 fragments (4 A, 2 B) of quadrant p (literal offsets = p*8192)
#define RD_Q0 { DSR(af[0], aA, 0);     DSR(af[1], aA, 512);   DSR(af[2], aA, 1024);  DSR(af[3], aA, 1536);  DSR(bf[0], bA, 0);     DSR(bf[1], bA, 512);   }
#define RD_Q1 { DSR(af[0], aA, 8192);  DSR(af[1], aA, 8704);  DSR(af[2], aA, 9216);  DSR(af[3], aA, 9728);  DSR(bf[0], bA, 8192);  DSR(bf[1], bA, 8704);  }
#define RD_Q2 { DSR(af[0], aA, 16384); DSR(af[1], aA, 16896); DSR(af[2], aA, 17408); DSR(af[3], aA, 17920); DSR(bf[0], bA, 16384); DSR(bf[1], bA, 16896); }
#define RD_Q3 { DSR(af[0], aA, 24576); DSR(af[1], aA, 25088); DSR(af[2], aA, 25600); DSR(af[3], aA, 26112); DSR(bf[0], bA, 24576); DSR(bf[1], bA, 25088); }

#define MFMA8                                                                          \
  {                                                                                    \
    __builtin_amdgcn_s_setprio(1);                                                     \
    _Pragma("unroll") for (int i_ = 0; i_ < 4; ++i_)                                   \
        _Pragma("unroll") for (int j_ = 0; j_ < 2; ++j_) acc[i_][j_] =                 \
            __builtin_amdgcn_mfma_i32_32x32x32_i8(af[i_], bf[j_], acc[i_][j_],         \
                                                  0, 0, 0);                            \
    __builtin_amdgcn_s_setprio(0);                                                     \
  }

// phase 0: VALIDATED entry — stage next pair, counted vmcnt (tile kb's 8
// landed, next tile's 2 in flight), barrier, THEN read buf[cur]. Fixes the
// round-10 race (reads of a not-yet-validated buffer).
#define PHASE0(STG, WAITC)               \
  {                                      \
    STG;                                 \
    WAITC;                               \
    __builtin_amdgcn_s_barrier();        \
    __builtin_amdgcn_sched_barrier(0);   \
    RD_Q0;                               \
    LGKM(0);                             \
    __builtin_amdgcn_sched_barrier(0);   \
    MFMA8;                               \
    __builtin_amdgcn_s_barrier();        \
  }

// phases 1-3: m201 read-hiding form — reads (of the already-validated buf)
// + stage pair BEFORE barrier (barrier wait hides read latency), lgkm(0)
// after, MFMA cluster, trailing barrier.
#define PHASE(RD, STG)                   \
  {                                      \
    RD;                                  \
    STG;                                 \
    __builtin_amdgcn_s_barrier();        \
    LGKM(0);                             \
    __builtin_amdgcn_sched_barrier(0);   \
    MFMA8;                               \
    __builtin_amdgcn_s_barrier();        \
  }

// 256x256 tile, BK=128 B, 8 waves (2 row-halves x 4 col-quarters), wave-tile
// 128x64, mfma_i32_32x32x32_i8, k-chunk-major LDS (conflict-free, PMC-
// verified). 8-barrier/tile m201 schedule with race-free phase 0; stage
// split 2-loads/phase (continuous VMEM stream); single counted vmcnt(2)
// per tile (never 0 mid-loop). XCD block swizzle.
__global__ __launch_bounds__(512, 2) void bitgemm32(const unsigned char* __restrict__ xq2,
                                                    const unsigned char* __restrict__ wu2,
                                                    const float2* __restrict__ scales,
                                                    const float* __restrict__ wsp,
                                                    float* __restrict__ out) {
  __shared__ __align__(16) unsigned char lds[131072];  // A [2][32K] | B [2][32K]

  const int tid = threadIdx.x;
  const int l = tid & 63;
  const int w = tid >> 6;  // 0..7
  const int wm = w >> 2;   // row half 0..1
  const int wn = w & 3;    // col quarter 0..3

  // XCD swizzle: 768 blocks (%8==0 -> bijective), bm-major within each XCD
  const int cpx = gridDim.x >> 3;
  const int swz = (blockIdx.x & 7) * cpx + (blockIdx.x >> 3);
  const int bn = swz & (GN - 1);
  const int bm = swz >> 4;

  // staging: thread t writes LDS chunk-slot (q*2 + (t>>8), row t&255); source
  // chunk c = kb*8 + q*2 + (t>>8) at the same row -> contiguous 4-KiB runs.
  const unsigned char* aBase =
      xq2 + ((size_t)(tid >> 8) * 4096 + (size_t)bn * 256 + (tid & 255)) * 16;
  const unsigned char* bBase =
      wu2 + ((size_t)(tid >> 8) * 12288 + (size_t)bm * 256 + (tid & 255)) * 16;
  const int ldsDst = tid * 16;

  // fragment read base offsets: lane l -> k-half h = l>>5, row/col = l&31
  const int aFB = (l >> 5) * 4096 + (wm * 128 + (l & 31)) * 16;
  const int bFB = (l >> 5) * 4096 + (wn * 64 + (l & 31)) * 16;
  const unsigned ldsBase = (unsigned)(size_t)lds;

  i32x16 acc[4][2];
#pragma unroll
  for (int i = 0; i < 4; ++i)
#pragma unroll
    for (int j = 0; j < 2; ++j)
#pragma unroll
      for (int r = 0; r < 16; ++r) acc[i][j][r] = 0;

  // stage quarter q of tile kb into buffer buf (2 gloads: 1 A + 1 B)
  auto stageQ = [&](int buf, int kb, int q) {
    __builtin_amdgcn_global_load_lds(
        (const __attribute__((address_space(1))) void*)(aBase + (size_t)kb * 524288 +
                                                        (size_t)q * 131072),
        (__attribute__((address_space(3))) void*)(lds + buf * 32768 + ldsDst + q * 8192), 16, 0,
        0);
    __builtin_amdgcn_global_load_lds(
        (const __attribute__((address_space(1))) void*)(bBase + (size_t)kb * 1572864 +
                                                        (size_t)q * 393216),
        (__attribute__((address_space(3))) void*)(lds + 65536 + buf * 32768 + ldsDst + q * 8192),
        16, 0, 0);
  };

  i32x4 af[4], bf[2];

  // prologue: stage all of tile 0
#pragma unroll
  for (int q = 0; q < 4; ++q) stageQ(0, 0, q);

  for (int kb = 0; kb < NT_K; ++kb) {
    const int cur = kb & 1;
    const int nbuf = cur ^ 1;
    const bool pf = (kb + 1 < NT_K);
    const unsigned aA = ldsBase + cur * 32768 + aFB;
    const unsigned bA = ldsBase + 65536 + cur * 32768 + bFB;

    if (pf) {
      PHASE0(stageQ(nbuf, kb + 1, 0), asm volatile("s_waitcnt vmcnt(2)" ::: "memory"));
      PHASE(RD_Q1, stageQ(nbuf, kb + 1, 1));
      PHASE(RD_Q2, stageQ(nbuf, kb + 1, 2));
      PHASE(RD_Q3, stageQ(nbuf, kb + 1, 3));
    } else {
      PHASE0(, asm volatile("s_waitcnt vmcnt(0)" ::: "memory"));
      PHASE(RD_Q1, );
      PHASE(RD_Q2, );
      PHASE(RD_Q3, );
    }
  }

  // epilogue: out = (dot_codes - rowsum) * weight_scale * act_scale
  // 32x32 C/D: col = l&31, row = (r&3) + 8*(r>>2) + 4*(l>>5)
  const float wsc = wsp[0];
#pragma unroll
  for (int i = 0; i < 4; ++i) {
#pragma unroll
    for (int r = 0; r < 16; ++r) {
      const int n = bn * BM + wm * 128 + i * 32 + (r & 3) + 8 * (r >> 2) + 4 * (l >> 5);
      const float2 sc = scales[n];
      const float f = wsc * sc.x;
      float* orow = out + (size_t)n * M_DIM + bm * BN + wn * 64 + (l & 31);
#pragma unroll
      for (int j = 0; j < 2; ++j) orow[j * 32] = ((float)acc[i][j][r] - sc.y) * f;
    }
  }
}

extern "C" void kernel_launch(void* const* d_in, const int* in_sizes, int n_in,
                              void* d_out, int out_size, void* d_ws, size_t ws_size,
                              hipStream_t stream) {
  const float* x = (const float*)d_in[0];
  const int* wp = (const int*)d_in[1];
  const float* wsp = (const float*)d_in[2];
  float* out = (float*)d_out;
  const int N = in_sizes[0] / K_DIM;  // 4096 tokens

  float2* scales = (float2*)d_ws;                                  // N * 8 B
  u32x4* xq2 = (u32x4*)((char*)d_ws + 32768);                      // 16 MB, k-major
  u32x4* wu2 = (u32x4*)((char*)d_ws + 32768 + (size_t)N * K_DIM);  // 48 MB, k-major

  aux_kernel<<<4096 + 1536, 256, 0, stream>>>(x, wp, xq2, wu2, scales);
  const int grid = (N / BM) * GM;  // 768
  bitgemm32<<<grid, 512, 0, stream>>>((const unsigned char*)xq2, (const unsigned char*)wu2,
                                      scales, wsp, out);
}